// Round 12
// baseline (224.468 us; speedup 1.0000x reference)
//
#include <hip/hip_runtime.h>
#include <hip/hip_fp16.h>
#include <stdint.h>

#define K_DIM 4096
#define N_OUT 4096
#define BM 256
#define BN 128
#define BKB 64  // K-bytes per step = 2 MFMA K-slices

typedef __attribute__((ext_vector_type(4))) int int32x4;
typedef __attribute__((ext_vector_type(16))) int int32x16;

// ---------------- per-token int4 activation quantization ----------------
// x_scale = max(x_max/7, fp16(1e-5)); x_q = clip(rint(x/x_scale), -8, 7).
// All f32; no intermediate fp16 rounding (matches harness np reference).
__global__ __launch_bounds__(256) void quant_x(const float* __restrict__ x,
                                               int8_t* __restrict__ xq,
                                               float* __restrict__ xs) {
  const int row = blockIdx.x;
  const int t = threadIdx.x;
  const float4* xr = (const float4*)(x + (size_t)row * K_DIM);
  float4 v[4];
  float m = 0.f;
#pragma unroll
  for (int i = 0; i < 4; ++i) {
    v[i] = xr[t * 4 + i];
    m = fmaxf(m, fmaxf(fmaxf(fabsf(v[i].x), fabsf(v[i].y)),
                       fmaxf(fabsf(v[i].z), fabsf(v[i].w))));
  }
#pragma unroll
  for (int off = 32; off > 0; off >>= 1) m = fmaxf(m, __shfl_xor(m, off));
  __shared__ float wmax[4];
  if ((t & 63) == 0) wmax[t >> 6] = m;
  __syncthreads();
  m = fmaxf(fmaxf(wmax[0], wmax[1]), fmaxf(wmax[2], wmax[3]));

  const float eps = 1.0013580322265625e-05f;  // fp16(1e-5) as f32
  const float xscale = fmaxf(m / 7.0f, eps);
  if (t == 0) xs[row] = xscale;

  uint32_t p[4];
#pragma unroll
  for (int g = 0; g < 4; ++g) {
    const float* fv = (const float*)&v[g];
    uint32_t w = 0;
#pragma unroll
    for (int j = 0; j < 4; ++j) {
      float r = rintf(fv[j] / xscale);
      r = fminf(fmaxf(r, -8.f), 7.f);
      w |= ((uint32_t)(uint8_t)(int8_t)(int)r) << (8 * j);
    }
    p[g] = w;
  }
  *(uint4*)(xq + (size_t)row * K_DIM + t * 16) = *(uint4*)p;
}

// ---------------- weight pack: int32 -> int8, FRAGMENT-MAJOR ----------------
// block b = nfrag*128 + kslice; each block 1024B in MFMA lane order.
__global__ __launch_bounds__(256) void pack_w(const int* __restrict__ w,
                                              uint32_t* __restrict__ wqf) {
  const int c = blockIdx.x * 256 + threadIdx.x;  // one thread per 16B chunk
  const int blk = c >> 6;
  const int l = c & 63;
  const int row = ((blk >> 7) << 5) + (l & 31);
  const int k = ((blk & 127) << 5) + ((l >> 5) << 4);
  const int4* src = (const int4*)(w + (size_t)row * K_DIM + k);  // 16 ints
  uint32_t p[4];
#pragma unroll
  for (int g = 0; g < 4; ++g) {
    const int4 v = src[g];
    p[g] = (uint32_t)(v.x & 255) | ((uint32_t)(v.y & 255) << 8) |
           ((uint32_t)(v.z & 255) << 16) | ((uint32_t)(v.w & 255) << 24);
  }
  *(uint4*)(wqf + (size_t)c * 4) = *(uint4*)p;
}

// ---------------- i8 GEMM: out = dequant(xq . wq^T) ----------------
// r12: TLP round. 256x128 tile, 8 waves (4m x 2n), wave tile 64x64
// (acc = 2x2 frags = 64 AGPR), both A AND B staged to LDS (fragment-
// contiguous, 2-deep, 48KB), target <=128 total regs/wave ->
// __launch_bounds__(512,4) -> 4 waves/SIMD = 2 independent blocks/CU
// (double the TLP of r7-r11, which were all pinned at 2 waves/SIMD by
// the 252-reg footprint). Known LDS-pacing ceiling ~55% MfmaUtil.
// Per step: stage(s+1) [3 glds/wave], 8 ds_read + 8 MFMA, vmcnt(0)+barrier.
__global__ __launch_bounds__(512, 4) void gemm_w4a4(
    const int8_t* __restrict__ xq, const uint8_t* __restrict__ wqf,
    const float* __restrict__ xs, const float* __restrict__ wscale,
    float* __restrict__ out, int M) {
  __shared__ uint8_t lds[2][24576];  // [buf][A:16KB (16 blk) | B:8KB (8 blk)]

  // Swizzle: 1024 blocks, 8 XCDs, 128/XCD; each XCD owns 4 A-panels (mt),
  // consecutive i_loc share mt -> A L2-resident per XCD.
  const int bid = blockIdx.x;
  const int xcd = bid & 7;
  const int i_loc = bid >> 3;            // 0..127
  const int mt = xcd * 4 + (i_loc & 3);  // 0..31, XCD-exclusive
  const int nt = i_loc >> 2;             // 0..31
  const int tm = mt * BM;
  const int tn = nt * BN;

  const int t = threadIdx.x;  // 0..511
  const int l = t & 63;
  const int wv = t >> 6;      // 0..7
  const int wm = wv >> 1;     // 0..3
  const int wn = wv & 1;      // 0..1

  // A staging: wave wv stages fa=wv, ks=0/1 (blocks 2wv, 2wv+1)
  const uint8_t* gAw = (const uint8_t*)xq +
                       (size_t)(tm + wv * 32 + (l & 31)) * K_DIM +
                       ((l >> 5) << 4);
  // B staging: wave wv stages B block wv (fb = wv>>1, ksb = wv&1)
  const uint8_t* gBw = wqf +
                       ((size_t)(nt * 4 + (wv >> 1)) * 128 + (wv & 1)) * 1024 +
                       (size_t)l * 16;

  int32x16 acc[2][2] = {};

  auto stage = [&](int buf, int sg) {
    const int ktb = (sg & 63) * BKB;
#pragma unroll
    for (int j = 0; j < 2; ++j) {
      __builtin_amdgcn_global_load_lds(
          (const __attribute__((address_space(1))) uint32_t*)(gAw + ktb + j * 32),
          (__attribute__((address_space(3))) uint32_t*)(
              &lds[buf][(wv * 2 + j) * 1024 + l * 16]),
          16, 0, 0);
    }
    __builtin_amdgcn_global_load_lds(
        (const __attribute__((address_space(1))) uint32_t*)(
            gBw + (size_t)(sg & 63) * 2048),
        (__attribute__((address_space(3))) uint32_t*)(
            &lds[buf][16384 + wv * 1024 + l * 16]),
        16, 0, 0);
  };

  const int nsteps = K_DIM / BKB;  // 64

  stage(0, 0);
  asm volatile("s_waitcnt vmcnt(0)" ::: "memory");
  __builtin_amdgcn_s_barrier();

  for (int s = 0; s < nsteps; ++s) {
    const int buf = s & 1;
    stage(buf ^ 1, s + 1);  // 3 glds (wrapped dead at tail)

    // frag (i, ks): A at wm*4096 + i*2048 + ks*1024; B at 16384 + wn*4096 + ...
    const uint8_t* aB = &lds[buf][wm * 4096 + l * 16];
    const uint8_t* bB = &lds[buf][16384 + wn * 4096 + l * 16];
    int32x4 a0[2], a1[2], b0[2], b1[2];
#pragma unroll
    for (int i = 0; i < 2; ++i) {
      a0[i] = *(const int32x4*)(aB + i * 2048);
      b0[i] = *(const int32x4*)(bB + i * 2048);
      a1[i] = *(const int32x4*)(aB + i * 2048 + 1024);
      b1[i] = *(const int32x4*)(bB + i * 2048 + 1024);
    }
#pragma unroll
    for (int i = 0; i < 2; ++i)
#pragma unroll
      for (int j = 0; j < 2; ++j)
        acc[i][j] = __builtin_amdgcn_mfma_i32_32x32x32_i8(a0[i], b0[j],
                                                          acc[i][j], 0, 0, 0);
#pragma unroll
    for (int i = 0; i < 2; ++i)
#pragma unroll
      for (int j = 0; j < 2; ++j)
        acc[i][j] = __builtin_amdgcn_mfma_i32_32x32x32_i8(a1[i], b1[j],
                                                          acc[i][j], 0, 0, 0);

    asm volatile("s_waitcnt vmcnt(0)" ::: "memory");
    __builtin_amdgcn_s_barrier();
  }

  // epilogue: dequant + fp16-round, write f32
  const int colbase = tn + wn * 64;
  const int rowbase = tm + wm * 64 + 4 * (l >> 5);
#pragma unroll
  for (int m = 0; m < 2; ++m) {
#pragma unroll
    for (int n = 0; n < 2; ++n) {
      const int col = colbase + n * 32 + (l & 31);
      const float wsc = wscale[col];
#pragma unroll
      for (int j = 0; j < 16; ++j) {
        const int row = rowbase + m * 32 + (j & 3) + 8 * (j >> 2);
        const float val = (float)acc[m][n][j] * (xs[row] * wsc);
        out[(size_t)row * N_OUT + col] = __half2float(__float2half(val));
      }
    }
  }
}

extern "C" void kernel_launch(void* const* d_in, const int* in_sizes, int n_in,
                              void* d_out, int out_size, void* d_ws, size_t ws_size,
                              hipStream_t stream) {
  const float* x = (const float*)d_in[0];    // fp16 values as f32
  const int* w = (const int*)d_in[1];        // int4-range values as i32
  const float* wsc = (const float*)d_in[2];  // fp16 values as f32
  float* out = (float*)d_out;

  const int M = in_sizes[0] / K_DIM;  // 8192 tokens

  uint8_t* ws = (uint8_t*)d_ws;
  int8_t* xq = (int8_t*)ws;                              // M*K bytes
  uint8_t* wqf = ws + (size_t)M * K_DIM;                 // N*K bytes (frag-major)
  float* xs = (float*)(ws + (size_t)M * K_DIM + (size_t)N_OUT * K_DIM);

  quant_x<<<M, 256, 0, stream>>>(x, xq, xs);
  pack_w<<<(N_OUT * K_DIM / 16) / 256, 256, 0, stream>>>(w, (uint32_t*)wqf);
  gemm_w4a4<<<(M / BM) * (N_OUT / BN), 512, 0, stream>>>(
      xq, wqf, xs, wsc, out, M);
}

// Round 13
// 216.737 us; speedup vs baseline: 1.0357x; 1.0357x over previous
//
#include <hip/hip_runtime.h>
#include <hip/hip_fp16.h>
#include <stdint.h>

#define K_DIM 4096
#define N_OUT 4096
#define BM 256
#define BN 256
#define BKB 128  // K-bytes per step = 4 MFMA K-slices

typedef __attribute__((ext_vector_type(4))) int int32x4;
typedef __attribute__((ext_vector_type(16))) int int32x16;

// ---------------- per-token int4 activation quantization ----------------
// x_scale = max(x_max/7, fp16(1e-5)); x_q = clip(rint(x/x_scale), -8, 7).
// All f32; no intermediate fp16 rounding (matches harness np reference).
__global__ __launch_bounds__(256) void quant_x(const float* __restrict__ x,
                                               int8_t* __restrict__ xq,
                                               float* __restrict__ xs) {
  const int row = blockIdx.x;
  const int t = threadIdx.x;
  const float4* xr = (const float4*)(x + (size_t)row * K_DIM);
  float4 v[4];
  float m = 0.f;
#pragma unroll
  for (int i = 0; i < 4; ++i) {
    v[i] = xr[t * 4 + i];
    m = fmaxf(m, fmaxf(fmaxf(fabsf(v[i].x), fabsf(v[i].y)),
                       fmaxf(fabsf(v[i].z), fabsf(v[i].w))));
  }
#pragma unroll
  for (int off = 32; off > 0; off >>= 1) m = fmaxf(m, __shfl_xor(m, off));
  __shared__ float wmax[4];
  if ((t & 63) == 0) wmax[t >> 6] = m;
  __syncthreads();
  m = fmaxf(fmaxf(wmax[0], wmax[1]), fmaxf(wmax[2], wmax[3]));

  const float eps = 1.0013580322265625e-05f;  // fp16(1e-5) as f32
  const float xscale = fmaxf(m / 7.0f, eps);
  if (t == 0) xs[row] = xscale;

  uint32_t p[4];
#pragma unroll
  for (int g = 0; g < 4; ++g) {
    const float* fv = (const float*)&v[g];
    uint32_t w = 0;
#pragma unroll
    for (int j = 0; j < 4; ++j) {
      float r = rintf(fv[j] / xscale);
      r = fminf(fmaxf(r, -8.f), 7.f);
      w |= ((uint32_t)(uint8_t)(int8_t)(int)r) << (8 * j);
    }
    p[g] = w;
  }
  *(uint4*)(xq + (size_t)row * K_DIM + t * 16) = *(uint4*)p;
}

// ---------------- weight pack: int32 -> int8, FRAGMENT-MAJOR ----------------
// block b = nfrag*128 + kslice; each block 1024B in MFMA lane order.
__global__ __launch_bounds__(256) void pack_w(const int* __restrict__ w,
                                              uint32_t* __restrict__ wqf) {
  const int c = blockIdx.x * 256 + threadIdx.x;  // one thread per 16B chunk
  const int blk = c >> 6;
  const int l = c & 63;
  const int row = ((blk >> 7) << 5) + (l & 31);
  const int k = ((blk & 127) << 5) + ((l >> 5) << 4);
  const int4* src = (const int4*)(w + (size_t)row * K_DIM + k);  // 16 ints
  uint32_t p[4];
#pragma unroll
  for (int g = 0; g < 4; ++g) {
    const int4 v = src[g];
    p[g] = (uint32_t)(v.x & 255) | ((uint32_t)(v.y & 255) << 8) |
           ((uint32_t)(v.z & 255) << 16) | ((uint32_t)(v.w & 255) << 24);
  }
  *(uint4*)(wqf + (size_t)c * 4) = *(uint4*)p;
}

// ---------------- i8 GEMM: out = dequant(xq . wq^T) ----------------
// 256x256 tile, 8 waves (2m x 4n, 512 thr), wave tile 128x64, 32x32x32 i8.
// r13 = r8 skeleton (best validated: 165us, 36%) + deep prefetch:
//  1. A: LDS fragment-contiguous, 3-DEEP (3x32KB=96KB), staged 2 STEPS ahead
//     -> staging loads get ~2 bodies (~12k cyc) to land, covering L2-miss /
//     HBM-class latency (FETCH=2x inputs shows staging misses L2 often).
//  2. Issue order per step: loadB(s+1) BEFORE stageA(s+2). With in-order
//     vmcnt retire, next step's compiler wait on bB then does NOT drain the
//     deep A prefetch (the whole point of 2-ahead).
//  3. Counted vmcnt(12) per step: 12 newest = [B(s+1)x8, A(s+2)x4] stay in
//     flight; everything older (B(s), A(s+1)) retired -> A(s+1) landed for
//     next step. Never vmcnt(0) in the loop.
// Body: zero internal barriers, a0/a1 2-deep rotation, 32 MFMA (as r8).
__global__ __launch_bounds__(512, 2) void gemm_w4a4(
    const int8_t* __restrict__ xq, const uint8_t* __restrict__ wqf,
    const float* __restrict__ xs, const float* __restrict__ wscale,
    float* __restrict__ out, int M) {
  __shared__ uint8_t lds[3][32768];  // A only: 32 frag-blocks (8 fa x 4 ks)/buf

  // Swizzle: A-panels XCD-exclusive (L2-resident); concurrent blocks in an
  // XCD share A via L2.
  const int bid = blockIdx.x;
  const int xcd = bid & 7;
  const int i_loc = bid >> 3;            // 0..63
  const int mt = xcd * 4 + (i_loc & 3);  // 0..31, XCD-exclusive
  const int nt = i_loc >> 2;             // 0..15
  const int tm = mt * BM;
  const int tn = nt * BN;

  const int t = threadIdx.x;  // 0..511
  const int l = t & 63;
  const int wv = t >> 6;      // 0..7
  const int wm = wv >> 2;     // 0..1
  const int wn = wv & 3;      // 0..3

  // A staging source: lane l covers row (l&31), k-bytes (l>>5)*16
  const uint8_t* gA = (const uint8_t*)xq + (size_t)tm * K_DIM +
                      (size_t)(l & 31) * K_DIM + ((l >> 5) << 4);
  // B fragment-major bases for this wave's two n-frags
  const int nfrag0 = nt * 8 + wn * 2;
  const uint8_t* gB0 = wqf + ((size_t)(nfrag0 * 128) << 10) + l * 16;
  const uint8_t* gB1 = wqf + ((size_t)((nfrag0 + 1) * 128) << 10) + l * 16;

  int32x16 acc[4][2] = {};

  // stage quarter q of tile (ktb) into buf: block bIdx = q*8 + wv
  // (fa = bIdx>>2, ks = bIdx&3); LDS dest = q*8192 + t*16 (wave-uniform base
  // + lane*16, as global_load_lds requires).
  auto stageA4 = [&](int buf, int ktb) {
#pragma unroll
    for (int q = 0; q < 4; ++q) {
      const int bIdx = q * 8 + wv;
      __builtin_amdgcn_global_load_lds(
          (const __attribute__((address_space(1))) uint32_t*)(
              gA + (size_t)((bIdx >> 2) * 32) * K_DIM + (bIdx & 3) * 32 + ktb),
          (__attribute__((address_space(3))) uint32_t*)(
              &lds[buf][q * 8192 + t * 16]),
          16, 0, 0);
    }
  };

  // load 8 B frags (2 nfrag x 4 ks) for step sw
  auto loadB = [&](int32x4 (&b)[8], int sw) {
#pragma unroll
    for (int ks = 0; ks < 4; ++ks) {
      b[ks] = *(const int32x4*)(gB0 + ((size_t)(sw * 4 + ks) << 10));
      b[4 + ks] = *(const int32x4*)(gB1 + ((size_t)(sw * 4 + ks) << 10));
    }
  };

  const int nsteps = K_DIM / BKB;  // 32

  // one step, zero internal barriers; a-regs rotate a0/a1 (static indices)
  auto do_step = [&](int s, int32x4 (&bCur)[8], int32x4 (&bNext)[8]) {
    loadB(bNext, (s + 1) & 31);            // B(s+1) FIRST (ledger: see above)
    asm volatile("" ::: "memory");         // pin: B-loads before A-stages
    stageA4((s + 2) % 3, ((s + 2) & 31) * BKB);  // A(s+2), 2 steps ahead

    const uint8_t* base = &lds[s % 3][wm * 16384 + l * 16];
    int32x4 a0[4], a1[4];
#pragma unroll
    for (int m = 0; m < 4; ++m)
      a0[m] = *(const int32x4*)(base + m * 4096 + 0 * 1024);

#define MFMA8(A, ks)                                                       \
  _Pragma("unroll") for (int m = 0; m < 4; ++m) {                          \
    acc[m][0] =                                                            \
        __builtin_amdgcn_mfma_i32_32x32x32_i8(A[m], bCur[ks], acc[m][0],   \
                                              0, 0, 0);                    \
    acc[m][1] = __builtin_amdgcn_mfma_i32_32x32x32_i8(                     \
        A[m], bCur[4 + ks], acc[m][1], 0, 0, 0);                           \
  }

#pragma unroll
    for (int m = 0; m < 4; ++m)
      a1[m] = *(const int32x4*)(base + m * 4096 + 1 * 1024);
    MFMA8(a0, 0);
#pragma unroll
    for (int m = 0; m < 4; ++m)
      a0[m] = *(const int32x4*)(base + m * 4096 + 2 * 1024);
    MFMA8(a1, 1);
#pragma unroll
    for (int m = 0; m < 4; ++m)
      a1[m] = *(const int32x4*)(base + m * 4096 + 3 * 1024);
    MFMA8(a0, 2);
    MFMA8(a1, 3);
#undef MFMA8

    // 12 newest = [B(s+1)x8, A(s+2)x4] stay; older (B(s), A(s+1)) retired.
    asm volatile("s_waitcnt vmcnt(12)" ::: "memory");
    __builtin_amdgcn_s_barrier();
  };

  // prologue: A(0)->buf0, B(0)->bX, A(1)->buf1; vmcnt(12) retires A(0)
  int32x4 bX[8], bY[8];
  stageA4(0, 0);
  asm volatile("" ::: "memory");
  loadB(bX, 0);
  asm volatile("" ::: "memory");
  stageA4(1, BKB);
  asm volatile("s_waitcnt vmcnt(12)" ::: "memory");
  __builtin_amdgcn_s_barrier();

  for (int s = 0; s < nsteps; s += 2) {
    do_step(s, bX, bY);      // consumes bX, prefetches into bY
    do_step(s + 1, bY, bX);  // consumes bY, prefetches into bX
  }
  asm volatile("s_waitcnt vmcnt(0)" ::: "memory");  // drain dead prefetches

  // epilogue: dequant + fp16-round, write f32
  const int colbase = tn + wn * 64;
  const int rowbase = tm + wm * 128 + 4 * (l >> 5);
#pragma unroll
  for (int m = 0; m < 4; ++m) {
#pragma unroll
    for (int n = 0; n < 2; ++n) {
      const int col = colbase + n * 32 + (l & 31);
      const float wsc = wscale[col];
#pragma unroll
      for (int j = 0; j < 16; ++j) {
        const int row = rowbase + m * 32 + (j & 3) + 8 * (j >> 2);
        const float val = (float)acc[m][n][j] * (xs[row] * wsc);
        out[(size_t)row * N_OUT + col] = __half2float(__float2half(val));
      }
    }
  }
}

extern "C" void kernel_launch(void* const* d_in, const int* in_sizes, int n_in,
                              void* d_out, int out_size, void* d_ws, size_t ws_size,
                              hipStream_t stream) {
  const float* x = (const float*)d_in[0];    // fp16 values as f32
  const int* w = (const int*)d_in[1];        // int4-range values as i32
  const float* wsc = (const float*)d_in[2];  // fp16 values as f32
  float* out = (float*)d_out;

  const int M = in_sizes[0] / K_DIM;  // 8192 tokens

  uint8_t* ws = (uint8_t*)d_ws;
  int8_t* xq = (int8_t*)ws;                              // M*K bytes
  uint8_t* wqf = ws + (size_t)M * K_DIM;                 // N*K bytes (frag-major)
  float* xs = (float*)(ws + (size_t)M * K_DIM + (size_t)N_OUT * K_DIM);

  quant_x<<<M, 256, 0, stream>>>(x, xq, xs);
  pack_w<<<(N_OUT * K_DIM / 16) / 256, 256, 0, stream>>>(w, (uint32_t*)wqf);
  gemm_w4a4<<<(M / BM) * (N_OUT / BN), 512, 0, stream>>>(
      xq, wqf, xs, wsc, out, M);
}

// Round 14
// 194.109 us; speedup vs baseline: 1.1564x; 1.1166x over previous
//
#include <hip/hip_runtime.h>
#include <hip/hip_fp16.h>
#include <stdint.h>

#define K_DIM 4096
#define N_OUT 4096
#define BM 256
#define BN 256
#define BKB 64  // K-bytes per step = 2 MFMA K-slices

typedef __attribute__((ext_vector_type(4))) int int32x4;
typedef __attribute__((ext_vector_type(16))) int int32x16;

// ---------------- per-token int4 activation quantization ----------------
// x_scale = max(x_max/7, fp16(1e-5)); x_q = clip(rint(x/x_scale), -8, 7).
// All f32; no intermediate fp16 rounding (matches harness np reference).
__global__ __launch_bounds__(256) void quant_x(const float* __restrict__ x,
                                               int8_t* __restrict__ xq,
                                               float* __restrict__ xs) {
  const int row = blockIdx.x;
  const int t = threadIdx.x;
  const float4* xr = (const float4*)(x + (size_t)row * K_DIM);
  float4 v[4];
  float m = 0.f;
#pragma unroll
  for (int i = 0; i < 4; ++i) {
    v[i] = xr[t * 4 + i];
    m = fmaxf(m, fmaxf(fmaxf(fabsf(v[i].x), fabsf(v[i].y)),
                       fmaxf(fabsf(v[i].z), fabsf(v[i].w))));
  }
#pragma unroll
  for (int off = 32; off > 0; off >>= 1) m = fmaxf(m, __shfl_xor(m, off));
  __shared__ float wmax[4];
  if ((t & 63) == 0) wmax[t >> 6] = m;
  __syncthreads();
  m = fmaxf(fmaxf(wmax[0], wmax[1]), fmaxf(wmax[2], wmax[3]));

  const float eps = 1.0013580322265625e-05f;  // fp16(1e-5) as f32
  const float xscale = fmaxf(m / 7.0f, eps);
  if (t == 0) xs[row] = xscale;

  uint32_t p[4];
#pragma unroll
  for (int g = 0; g < 4; ++g) {
    const float* fv = (const float*)&v[g];
    uint32_t w = 0;
#pragma unroll
    for (int j = 0; j < 4; ++j) {
      float r = rintf(fv[j] / xscale);
      r = fminf(fmaxf(r, -8.f), 7.f);
      w |= ((uint32_t)(uint8_t)(int8_t)(int)r) << (8 * j);
    }
    p[g] = w;
  }
  *(uint4*)(xq + (size_t)row * K_DIM + t * 16) = *(uint4*)p;
}

// ---------------- weight pack: int32 -> int8, FRAGMENT-MAJOR ----------------
// block b = nfrag*128 + kslice; each block 1024B in MFMA lane order.
__global__ __launch_bounds__(256) void pack_w(const int* __restrict__ w,
                                              uint32_t* __restrict__ wqf) {
  const int c = blockIdx.x * 256 + threadIdx.x;  // one thread per 16B chunk
  const int blk = c >> 6;
  const int l = c & 63;
  const int row = ((blk >> 7) << 5) + (l & 31);
  const int k = ((blk & 127) << 5) + ((l >> 5) << 4);
  const int4* src = (const int4*)(w + (size_t)row * K_DIM + k);  // 16 ints
  uint32_t p[4];
#pragma unroll
  for (int g = 0; g < 4; ++g) {
    const int4 v = src[g];
    p[g] = (uint32_t)(v.x & 255) | ((uint32_t)(v.y & 255) << 8) |
           ((uint32_t)(v.z & 255) << 16) | ((uint32_t)(v.w & 255) << 24);
  }
  *(uint4*)(wqf + (size_t)c * 4) = *(uint4*)p;
}

// ---------------- i8 GEMM: out = dequant(xq . wq^T) ----------------
// r14: full-fidelity m201 (8-phase bf16 template) port, i8-adapted.
// 256x256 tile, 8 waves (2m x 4n, 512 thr), wave tile 128x64, 32x32x32 i8.
// BK=64B (2 kslices); 64 steps; 2 phases/step; 3-deep LDS (3 x [A16K|B16K]).
// Phase = {ds_reads -> 2 stage-glds -> BARRIER -> lgkmcnt(0)+sched_barrier(0)
//          -> setprio(1) + 8 MFMA + setprio(0) -> BARRIER}.
// P1: read A(m0,m1)x(ks0,ks1) + B(n0,n1)x(ks0,ks1) [8 rds], stage A(s+2).
// P2: read A(m2,m3) [4 rds], stage B(s+2); vmcnt(4) BEFORE closing barrier
//     (retires (s+1)'s 4 staging glds block-wide; (s+2)'s 4 stay in flight;
//     never vmcnt(0) in the loop).
// WAR: stage(s+2) targets buf[(s-1)%3], whose reads finished >=2 barriers ago.
__global__ __launch_bounds__(512, 2) void gemm_w4a4(
    const int8_t* __restrict__ xq, const uint8_t* __restrict__ wqf,
    const float* __restrict__ xs, const float* __restrict__ wscale,
    float* __restrict__ out, int M) {
  __shared__ uint8_t lds[3][32768];  // [buf][A: 16 blk x 1KB | B: 16 blk x 1KB]

  // Swizzle (validated r8): A-panels XCD-exclusive, L2-resident.
  const int bid = blockIdx.x;
  const int xcd = bid & 7;
  const int i_loc = bid >> 3;            // 0..63
  const int mt = xcd * 4 + (i_loc & 3);  // 0..31, XCD-exclusive
  const int nt = i_loc >> 2;             // 0..15
  const int tm = mt * BM;
  const int tn = nt * BN;

  const int t = threadIdx.x;  // 0..511
  const int l = t & 63;
  const int wv = t >> 6;      // 0..7
  const int wm = wv >> 2;     // 0..1
  const int wn = wv & 3;      // 0..3

  // A staging source (validated r2 lane map): row (l&31), k-chunk (l>>5)*16
  const uint8_t* gA = (const uint8_t*)xq +
                      (size_t)(tm + wv * 32 + (l & 31)) * K_DIM +
                      ((l >> 5) << 4);
  // B staging source: frag-major wqf, wave wv stages nfrag (nt*8+wv)
  const uint8_t* gB = wqf + (size_t)(nt * 8 + wv) * 131072 + (size_t)l * 16;

  int32x16 acc[4][2] = {};

  // stage A of step ss into buf: blocks (fa=wv, ks=j) at (wv*2+j)*1024
  auto stageA2 = [&](int buf, int ss) {
#pragma unroll
    for (int j = 0; j < 2; ++j) {
      __builtin_amdgcn_global_load_lds(
          (const __attribute__((address_space(1))) uint32_t*)(
              gA + ss * BKB + j * 32),
          (__attribute__((address_space(3))) uint32_t*)(
              &lds[buf][(wv * 2 + j) * 1024 + l * 16]),
          16, 0, 0);
    }
  };
  // stage B of step ss into buf: kslices (ss*2+j) -> 16384 + (wv*2+j)*1024
  auto stageB2 = [&](int buf, int ss) {
#pragma unroll
    for (int j = 0; j < 2; ++j) {
      __builtin_amdgcn_global_load_lds(
          (const __attribute__((address_space(1))) uint32_t*)(
              gB + ((size_t)(ss * 2 + j) << 10)),
          (__attribute__((address_space(3))) uint32_t*)(
              &lds[buf][16384 + (wv * 2 + j) * 1024 + l * 16]),
          16, 0, 0);
    }
  };

#define PHASE_OPEN()                                    \
  __builtin_amdgcn_s_barrier();                         \
  asm volatile("s_waitcnt lgkmcnt(0)" ::: "memory");    \
  __builtin_amdgcn_sched_barrier(0);                    \
  __builtin_amdgcn_s_setprio(1);

#define PHASE_CLOSE()                                   \
  __builtin_amdgcn_s_setprio(0);

  const int nsteps = K_DIM / BKB;  // 64

  // prologue: stage steps 0 (buf0) and 1 (buf1); retire step-0's 4 glds
  stageA2(0, 0);
  stageB2(0, 0);
  stageA2(1, 1);
  stageB2(1, 1);
  asm volatile("s_waitcnt vmcnt(4)" ::: "memory");
  __builtin_amdgcn_s_barrier();

  for (int s = 0; s < nsteps; ++s) {
    const int buf = s % 3;
    const int sbuf = (s + 2) % 3;
    const int ss = (s + 2) & 63;  // wrapped (dead-but-harmless at tail)
    const uint8_t* aB = &lds[buf][(wm * 4) * 2048 + l * 16];           // m=0 base
    const uint8_t* bB = &lds[buf][16384 + (wn * 2) * 2048 + l * 16];   // n=0 base

    // ---- Phase 1: m0,m1 x n0,n1 x ks0,ks1 ----
    int32x4 a[2][2], b[2][2];  // [m][ks], [n][ks]
#pragma unroll
    for (int m = 0; m < 2; ++m)
#pragma unroll
      for (int ks = 0; ks < 2; ++ks)
        a[m][ks] = *(const int32x4*)(aB + m * 2048 + ks * 1024);
#pragma unroll
    for (int n = 0; n < 2; ++n)
#pragma unroll
      for (int ks = 0; ks < 2; ++ks)
        b[n][ks] = *(const int32x4*)(bB + n * 2048 + ks * 1024);
    stageA2(sbuf, ss);
    PHASE_OPEN()
#pragma unroll
    for (int ks = 0; ks < 2; ++ks)
#pragma unroll
      for (int m = 0; m < 2; ++m)
#pragma unroll
        for (int n = 0; n < 2; ++n)
          acc[m][n] = __builtin_amdgcn_mfma_i32_32x32x32_i8(
              a[m][ks], b[n][ks], acc[m][n], 0, 0, 0);
    PHASE_CLOSE()
    __builtin_amdgcn_s_barrier();

    // ---- Phase 2: m2,m3 x n0,n1 x ks0,ks1 (b reused in regs) ----
    int32x4 c[2][2];
#pragma unroll
    for (int m = 0; m < 2; ++m)
#pragma unroll
      for (int ks = 0; ks < 2; ++ks)
        c[m][ks] = *(const int32x4*)(aB + (2 + m) * 2048 + ks * 1024);
    stageB2(sbuf, ss);
    PHASE_OPEN()
#pragma unroll
    for (int ks = 0; ks < 2; ++ks)
#pragma unroll
      for (int m = 0; m < 2; ++m)
#pragma unroll
        for (int n = 0; n < 2; ++n)
          acc[2 + m][n] = __builtin_amdgcn_mfma_i32_32x32x32_i8(
              c[m][ks], b[n][ks], acc[2 + m][n], 0, 0, 0);
    PHASE_CLOSE()
    // retire (s+1)'s 4 staging glds BEFORE the barrier (block-wide guarantee);
    // (s+2)'s 4 stay in flight — never vmcnt(0) in the loop.
    asm volatile("s_waitcnt vmcnt(4)" ::: "memory");
    __builtin_amdgcn_s_barrier();
  }
  asm volatile("s_waitcnt vmcnt(0)" ::: "memory");  // drain dead prefetches

#undef PHASE_OPEN
#undef PHASE_CLOSE

  // epilogue: dequant + fp16-round, write f32
  const int colbase = tn + wn * 64;
  const int rowbase = tm + wm * 128 + 4 * (l >> 5);
#pragma unroll
  for (int m = 0; m < 4; ++m) {
#pragma unroll
    for (int n = 0; n < 2; ++n) {
      const int col = colbase + n * 32 + (l & 31);
      const float wsc = wscale[col];
#pragma unroll
      for (int j = 0; j < 16; ++j) {
        const int row = rowbase + m * 32 + (j & 3) + 8 * (j >> 2);
        const float val = (float)acc[m][n][j] * (xs[row] * wsc);
        out[(size_t)row * N_OUT + col] = __half2float(__float2half(val));
      }
    }
  }
}

extern "C" void kernel_launch(void* const* d_in, const int* in_sizes, int n_in,
                              void* d_out, int out_size, void* d_ws, size_t ws_size,
                              hipStream_t stream) {
  const float* x = (const float*)d_in[0];    // fp16 values as f32
  const int* w = (const int*)d_in[1];        // int4-range values as i32
  const float* wsc = (const float*)d_in[2];  // fp16 values as f32
  float* out = (float*)d_out;

  const int M = in_sizes[0] / K_DIM;  // 8192 tokens

  uint8_t* ws = (uint8_t*)d_ws;
  int8_t* xq = (int8_t*)ws;                              // M*K bytes
  uint8_t* wqf = ws + (size_t)M * K_DIM;                 // N*K bytes (frag-major)
  float* xs = (float*)(ws + (size_t)M * K_DIM + (size_t)N_OUT * K_DIM);

  quant_x<<<M, 256, 0, stream>>>(x, xq, xs);
  pack_w<<<(N_OUT * K_DIM / 16) / 256, 256, 0, stream>>>(w, (uint32_t*)wqf);
  gemm_w4a4<<<(M / BM) * (N_OUT / BN), 512, 0, stream>>>(
      xq, wqf, xs, wsc, out, M);
}